// Round 1
// baseline (139.628 us; speedup 1.0000x reference)
//
#include <hip/hip_runtime.h>

#define NEG_INF (-__builtin_inff())

// Tiling:
//   block = 256 threads: 16 w-groups (4 w each) x 16 h-rows
//   each thread: 4 o x 1 h x 4 w = 16 outputs (16 acc VGPRs)
//   block tile: 4 o x 16 h x 64 w, grid = (4 h-tiles, 8 b, 16 o-groups) = 512 blocks
//   c staged in LDS in chunks of 8: xs[8][18][68] = 39 KB -> 2 blocks/CU
#define CCH 8
#define HB 16
#define LDSTR 68   // row stride 68 floats: rows 16B-aligned -> aligned ds_read_b128

__global__ __launch_bounds__(256, 2)
void maxplus_conv2d_kernel(const float* __restrict__ x,
                           const float* __restrict__ kern,
                           float* __restrict__ out) {
    __shared__ float xs[CCH][HB + 2][LDSTR];

    const int tid = threadIdx.x;
    const int wg  = tid & 15;          // w-group 0..15
    const int hr  = tid >> 4;          // h-row   0..15
    const int w0  = wg << 2;           // first w of this thread's 4

    const int h_base = blockIdx.x * HB;      // 0,16,32,48
    const int b      = blockIdx.y;           // 0..7
    const int o_base = blockIdx.z << 2;      // 0,4,...,60

    // w-halo columns (raw col 0 <-> gw=-1, raw col 65 <-> gw=64) are always
    // out of the 64-wide image -> -inf. Written once; main loads never touch them.
    for (int i = tid; i < CCH * (HB + 2); i += 256) {
        int cl = i / (HB + 2);
        int r  = i - cl * (HB + 2);
        xs[cl][r][0]  = NEG_INF;
        xs[cl][r][65] = NEG_INF;
    }

    float acc[4][4];
#pragma unroll
    for (int oo = 0; oo < 4; ++oo)
#pragma unroll
        for (int wi = 0; wi < 4; ++wi)
            acc[oo][wi] = NEG_INF;

    const float* xb = x + (size_t)b * 64 * 64 * 64;   // x[b]

    for (int cc = 0; cc < 64; cc += CCH) {
        __syncthreads();   // prev chunk fully consumed before overwrite

        // Stage chunk: CCH*18 rows x 16 float4 = 2304 items, 9 per thread.
        // Global float4 loads are 16B-aligned (image rows are 256B-aligned).
#pragma unroll
        for (int k = 0; k < (CCH * (HB + 2) * 16) / 256; ++k) {
            int it    = k * 256 + tid;
            int f4    = it & 15;             // float4 index within row
            int rowid = it >> 4;             // 0 .. CCH*18-1
            int cl    = rowid / (HB + 2);
            int r     = rowid - cl * (HB + 2);
            int gh    = h_base + r - 1;      // global x row, -1..64
            int c     = cc + cl;
            bool valid = (unsigned)gh < 64u;
            int  ghc   = valid ? gh : 0;
            float4 v = *(const float4*)(xb + (((size_t)c * 64 + ghc) * 64 + f4 * 4));
            float* dst = &xs[cl][r][1 + f4 * 4];
            dst[0] = valid ? v.x : NEG_INF;
            dst[1] = valid ? v.y : NEG_INF;
            dst[2] = valid ? v.z : NEG_INF;
            dst[3] = valid ? v.w : NEG_INF;
        }
        __syncthreads();

#pragma unroll
        for (int cl = 0; cl < CCH; ++cl) {
            const int c = cc + cl;

            // Kernel taps for this c and the block's 4 o-values: block-uniform
            // addresses -> scalar loads, values live in SGPRs.
            float kv[4][9];
#pragma unroll
            for (int oo = 0; oo < 4; ++oo) {
                const float* kp = kern + ((size_t)(o_base + oo) * 64 + c) * 9;
#pragma unroll
                for (int t = 0; t < 9; ++t) kv[oo][t] = kp[t];
            }

            // x window: rows hr..hr+2, raw cols w0..w0+5 (16B-aligned base)
            float xv[3][6];
#pragma unroll
            for (int r = 0; r < 3; ++r)
#pragma unroll
                for (int j = 0; j < 6; ++j)
                    xv[r][j] = xs[cl][hr + r][w0 + j];

#pragma unroll
            for (int oo = 0; oo < 4; ++oo)
#pragma unroll
                for (int wi = 0; wi < 4; ++wi) {
                    float m = acc[oo][wi];
#pragma unroll
                    for (int ki = 0; ki < 3; ++ki)
#pragma unroll
                        for (int kj = 0; kj < 3; ++kj)
                            m = fmaxf(m, xv[ki][wi + kj] + kv[oo][ki * 3 + kj]);
                    acc[oo][wi] = m;
                }
        }
    }

    // Store: float4 per o, coalesced across the 16 w-groups.
    const int h = h_base + hr;
#pragma unroll
    for (int oo = 0; oo < 4; ++oo) {
        float4 v = make_float4(acc[oo][0], acc[oo][1], acc[oo][2], acc[oo][3]);
        *(float4*)(out + ((((size_t)b * 64 + (o_base + oo)) * 64 + h) * 64 + w0)) = v;
    }
}

extern "C" void kernel_launch(void* const* d_in, const int* in_sizes, int n_in,
                              void* d_out, int out_size, void* d_ws, size_t ws_size,
                              hipStream_t stream) {
    const float* x    = (const float*)d_in[0];   // [8,64,64,64]
    const float* kern = (const float*)d_in[1];   // [64,64,3,3]
    float* out = (float*)d_out;                  // [8,64,64,64]

    dim3 grid(4, 8, 16);   // h-tiles, b, o-groups
    dim3 block(256);
    maxplus_conv2d_kernel<<<grid, block, 0, stream>>>(x, kern, out);
}